// Round 10
// baseline (147.845 us; speedup 1.0000x reference)
//
#include <hip/hip_runtime.h>
#include <hip/hip_fp16.h>

typedef __attribute__((ext_vector_type(8))) _Float16 f16x8;
typedef __attribute__((ext_vector_type(4))) float f32x4;
typedef __attribute__((ext_vector_type(4))) unsigned int u32x4;

__device__ __forceinline__ unsigned short f2h(float f) {
  __half h = __float2half(f);
  return __builtin_bit_cast(unsigned short, h);
}
__device__ __forceinline__ __half2 bc_h2(unsigned u) {
  return __builtin_bit_cast(__half2, u);
}

// ---------------------------------------------------------------------------
// Kernel A: prep. blocks 0..511: x NCHW fp32 -> NHWC fp16 xt[b][h][w][c].
// blocks 512..871: repack main_w -> wt[k][128][64], offset_w -> wot[k][32][64].
// ---------------------------------------------------------------------------
__global__ __launch_bounds__(256) void prep_all(
    const float* __restrict__ x, const float* __restrict__ mw,
    const float* __restrict__ ow, unsigned short* __restrict__ xt,
    unsigned short* __restrict__ wt, unsigned short* __restrict__ wot) {
  __shared__ float tile[64 * 129];
  int blk = blockIdx.x;
  int t = threadIdx.x;
  if (blk < 512) {
    const float* xrow = x + ((long)(blk >> 7) << 20) + ((blk & 127) << 7);
#pragma unroll
    for (int i = 0; i < 32; ++i) {
      int idx = t + (i << 8);          // c = idx>>7, w = idx&127
      tile[(idx >> 7) * 129 + (idx & 127)] =
          xrow[((long)(idx >> 7) << 14) + (idx & 127)];
    }
    __syncthreads();
    unsigned short* orow = xt + ((long)blk << 13);
#pragma unroll
    for (int i = 0; i < 32; ++i) {
      int idx = t + (i << 8);          // w = idx>>6, c = idx&63
      orow[idx] = f2h(tile[(idx & 63) * 129 + (idx >> 6)]);
    }
  } else {
    int idx = (blk - 512) * 256 + t;   // 0..92159
    if (idx < 73728) {
      int c = idx & 63;
      int o = (idx >> 6) & 127;
      int k = idx >> 13;
      wt[idx] = f2h(mw[o * 576 + c * 9 + k]);
    } else {
      int i2 = idx - 73728;
      int c = i2 & 63;
      int o = (i2 >> 6) & 31;
      int k = i2 >> 11;
      wot[i2] = (o < 18) ? f2h(ow[o * 576 + c * 9 + k]) : (unsigned short)0;
    }
  }
}

// ---------------------------------------------------------------------------
// Kernel B: offset conv 64->18 via f16 MFMA. Block = 32-px tile, 4 waves;
// wave wv -> (m-frag wv&1, 16-px column wv>>1). Grid 2048. No LDS/barriers.
// ---------------------------------------------------------------------------
__global__ __launch_bounds__(256) void offs_mfma(
    const unsigned short* __restrict__ xt, const unsigned short* __restrict__ wot,
    const float* __restrict__ ob, float* __restrict__ offs) {
  int l = blockIdx.x;
  int bid = ((l & 7) << 8) + (l >> 3);   // XCD swizzle
  int b = bid >> 9;
  int r9 = bid & 511;
  int h = r9 >> 2;
  int w0 = (r9 & 3) << 5;
  int t = threadIdx.x;
  int lane = t & 63;
  int wv = t >> 6;
  int mf = wv & 1;
  int pxb = w0 + ((wv >> 1) << 4);
  int l15 = lane & 15;
  int l4 = lane >> 4;
  int l4k = l4 << 3;

  f32x4 oacc = f32x4{0.f, 0.f, 0.f, 0.f};

  const unsigned short* xb = xt + ((long)b << 20);
  const unsigned short* wkb = wot + (((mf << 4) + l15) << 6) + l4k;

#pragma unroll 1
  for (int k = 0; k < 9; ++k) {
    int ky = k / 3, kx = k - 3 * ky;
    int y = h + ky - 1;
    bool yok = (unsigned)y < 128u;
    int yc = min(max(y, 0), 127);
    const unsigned short* xrow = xb + ((long)yc << 13);
    int px = pxb + l15 + kx - 1;
    bool pv = yok && ((unsigned)px < 128u);
    int pxo = min(max(px, 0), 127) << 6;
#pragma unroll
    for (int c0 = 0; c0 < 64; c0 += 32) {
      f16x8 bv = *(const f16x8*)(xrow + pxo + c0 + l4k);
      if (!pv) bv = f16x8{0, 0, 0, 0, 0, 0, 0, 0};
      f16x8 af = *(const f16x8*)(wkb + (k << 11) + c0);
      oacc = __builtin_amdgcn_mfma_f32_16x16x32_f16(af, bv, oacc, 0, 0, 0);
    }
  }

#pragma unroll
  for (int r = 0; r < 4; ++r) {
    int oc = (mf << 4) + (l4 << 2) + r;
    if (oc < 18)
      offs[((long)(b * 18 + oc) << 14) + (h << 7) + pxb + l15] = oacc[r] + ob[oc];
  }
}

// ---------------------------------------------------------------------------
// Kernel C: deformable conv, register-resident V (no V LDS, 1 barrier).
// Block = 64-px tile, 4 waves, grid 1024. Wave wv owns px column
// [w0+wv*16, +16) x ALL 128 out-ch: 8 m-frags, 1 n-frag.
// Lane (l15=px, l4=8ch-chunk) bilinear-gathers its own B-fragment for
// tap k directly into registers (4 corners x 16B x 2 c-halves), packed
// __hfma2 interp, feeds 16 MFMAs. Corner loads double-buffered across
// taps (issue k+1 before consuming k) to hide L2 latency under MFMA.
// LDS: 9 KB wtab only.
// ---------------------------------------------------------------------------
__global__ __launch_bounds__(256) void deform_mfma(
    const unsigned short* __restrict__ xt, const float* __restrict__ offs,
    const unsigned short* __restrict__ wt, const float* __restrict__ mb,
    float* __restrict__ out) {
  __shared__ uint4 wtab[9][64];

  int l = blockIdx.x;
  int bid = ((l & 7) << 7) + (l >> 3);   // XCD swizzle (1024 % 8 == 0)
  int b = bid >> 8;
  int r8b = bid & 255;
  int h = r8b >> 1;
  int w0 = (r8b & 1) << 6;
  int t = threadIdx.x;
  int lane = t & 63;
  int wv = t >> 6;
  int l15 = lane & 15;
  int l4 = lane >> 4;
  int l4k = l4 << 3;                     // ch offset within 32-ch half
  int pxf = (wv << 4) + l15;             // px-in-tile this lane serves

  // ---- sampling table: 576 = 9 taps x 64 px (one barrier) ----
  const float* ob_ = offs + ((long)(b * 18) << 14) + (h << 7) + w0;
  for (int idx = t; idx < 576; idx += 256) {
    int px = idx & 63, k = idx >> 6;
    int ky = k / 3, kx = k - 3 * ky;
    float dy = ob_[((2 * k) << 14) + px];
    float dx = ob_[((2 * k + 1) << 14) + px];
    float py = (float)(h - 1 + ky) + dy;
    float pxq = (float)(w0 + px - 1 + kx) + dx;
    float fy = floorf(py), fx = floorf(pxq);
    float wy = py - fy, wx = pxq - fx;
    int y0 = (int)fy, x0 = (int)fx;
    int y1 = y0 + 1, x1 = x0 + 1;
    bool vy0 = (unsigned)y0 < 128u, vy1 = (unsigned)y1 < 128u;
    bool vx0 = (unsigned)x0 < 128u, vx1 = (unsigned)x1 < 128u;
    float w00 = (vy0 && vx0) ? (1.f - wy) * (1.f - wx) : 0.f;
    float w01 = (vy0 && vx1) ? (1.f - wy) * wx : 0.f;
    float w10 = (vy1 && vx0) ? wy * (1.f - wx) : 0.f;
    float w11 = (vy1 && vx1) ? wy * wx : 0.f;
    int y0c = min(max(y0, 0), 127), y1c = min(max(y1, 0), 127);
    int x0c = min(max(x0, 0), 127), x1c = min(max(x1, 0), 127);
    wtab[k][px] = make_uint4(
        (unsigned)f2h(w00) | ((unsigned)f2h(w01) << 16),
        (unsigned)f2h(w10) | ((unsigned)f2h(w11) << 16),
        (unsigned)(unsigned short)y0c | ((unsigned)(unsigned short)y1c << 16),
        (unsigned)(unsigned short)x0c | ((unsigned)(unsigned short)x1c << 16));
  }
  __syncthreads();

  const unsigned short* xb = xt + ((long)b << 20);

  f32x4 acc[8];
#pragma unroll
  for (int m = 0; m < 8; ++m) acc[m] = f32x4{0.f, 0.f, 0.f, 0.f};

  // corner buffers: [c-half*4 + corner], 32 VGPR each
  u32x4 bufA[8], bufB[8];

  // issue tap-k corner loads for this lane's (px, 8ch x 2 halves)
  auto issue = [&](int k, u32x4* A) {
    uint4 e = wtab[k][pxf];
    int y0 = (int)(short)(e.z & 0xffff), y1 = (int)(short)(e.z >> 16);
    int x0 = (int)(short)(e.w & 0xffff), x1 = (int)(short)(e.w >> 16);
    const unsigned short* r0 = xb + (y0 << 13) + l4k;
    const unsigned short* r1 = xb + (y1 << 13) + l4k;
    int o0 = x0 << 6, o1 = x1 << 6;
    A[0] = *(const u32x4*)(r0 + o0);
    A[1] = *(const u32x4*)(r0 + o1);
    A[2] = *(const u32x4*)(r1 + o0);
    A[3] = *(const u32x4*)(r1 + o1);
    A[4] = *(const u32x4*)(r0 + o0 + 32);
    A[5] = *(const u32x4*)(r0 + o1 + 32);
    A[6] = *(const u32x4*)(r1 + o0 + 32);
    A[7] = *(const u32x4*)(r1 + o1 + 32);
  };

  // consume tap k: bilinear -> B-frag, 16 MFMAs
  auto consume = [&](int k, const u32x4* A) {
    uint4 e = wtab[k][pxf];
    __half2 w00 = bc_h2((e.x & 0xffffu) | (e.x << 16));
    __half2 w01 = bc_h2((e.x >> 16) | (e.x & 0xffff0000u));
    __half2 w10 = bc_h2((e.y & 0xffffu) | (e.y << 16));
    __half2 w11 = bc_h2((e.y >> 16) | (e.y & 0xffff0000u));
#pragma unroll
    for (int ch = 0; ch < 2; ++ch) {
      u32x4 rr;
#pragma unroll
      for (int j = 0; j < 4; ++j) {
        __half2 v = __hmul2(w00, bc_h2(A[ch * 4 + 0][j]));
        v = __hfma2(w01, bc_h2(A[ch * 4 + 1][j]), v);
        v = __hfma2(w10, bc_h2(A[ch * 4 + 2][j]), v);
        v = __hfma2(w11, bc_h2(A[ch * 4 + 3][j]), v);
        rr[j] = __builtin_bit_cast(unsigned, v);
      }
      f16x8 bv = __builtin_bit_cast(f16x8, rr);
      const unsigned short* wk =
          wt + (((k << 7) + l15) << 6) + (ch << 5) + l4k;
#pragma unroll
      for (int m = 0; m < 8; ++m) {
        f16x8 af = *(const f16x8*)(wk + (m << 10));   // +m*16 rows*64c
        acc[m] = __builtin_amdgcn_mfma_f32_16x16x32_f16(af, bv, acc[m], 0, 0, 0);
      }
    }
  };

  issue(0, bufA);
#pragma unroll
  for (int k = 0; k < 9; ++k) {
    u32x4* cur = (k & 1) ? bufB : bufA;
    u32x4* nxt = (k & 1) ? bufA : bufB;
    if (k < 8) issue(k + 1, nxt);
    consume(k, cur);
  }

  // ---- epilogue: D row = o (lane>>4)*4+reg, col = px (lane&15) ----
  int hw0 = (h << 7) + w0 + (wv << 4);
#pragma unroll
  for (int m = 0; m < 8; ++m) {
    int orow = (m << 4) + (l4 << 2);
#pragma unroll
    for (int r = 0; r < 4; ++r)
      out[((long)(b * 128 + orow + r) << 14) + hw0 + l15] =
          acc[m][r] + mb[orow + r];
  }
}

extern "C" void kernel_launch(void* const* d_in, const int* in_sizes, int n_in,
                              void* d_out, int out_size, void* d_ws, size_t ws_size,
                              hipStream_t stream) {
  const float* x  = (const float*)d_in[0];
  const float* ow = (const float*)d_in[1];
  const float* ob = (const float*)d_in[2];
  const float* mw = (const float*)d_in[3];
  const float* mb = (const float*)d_in[4];
  float* out  = (float*)d_out;
  unsigned short* xt  = (unsigned short*)d_ws;                      // 8 MB
  unsigned short* wt  = (unsigned short*)((char*)d_ws + 8388608);   // 144 KB
  unsigned short* wot = (unsigned short*)((char*)d_ws + 8536064);   // 36 KB
  float* offs = (float*)((char*)d_ws + 8572928);                    // 4.5 MB

  prep_all<<<872, 256, 0, stream>>>(x, mw, ow, xt, wt, wot);
  offs_mfma<<<2048, 256, 0, stream>>>(xt, wot, ob, offs);
  deform_mfma<<<1024, 256, 0, stream>>>(xt, offs, wt, mb, out);
}

// Round 11
// 78.998 us; speedup vs baseline: 1.8715x; 1.8715x over previous
//
#include <hip/hip_runtime.h>
#include <hip/hip_fp16.h>

typedef __attribute__((ext_vector_type(8))) _Float16 f16x8;
typedef __attribute__((ext_vector_type(4))) float f32x4;
typedef __attribute__((ext_vector_type(4))) unsigned int u32x4;

__device__ __forceinline__ unsigned short f2h(float f) {
  __half h = __float2half(f);
  return __builtin_bit_cast(unsigned short, h);
}
__device__ __forceinline__ __half2 bc_h2(unsigned u) {
  return __builtin_bit_cast(__half2, u);
}

// ---------------------------------------------------------------------------
// Kernel A: prep. blocks 0..511: x NCHW fp32 -> NHWC fp16 xt[b][h][w][c].
// blocks 512..871: repack main_w -> wt[k][128][64], offset_w -> wot[k][32][64].
// ---------------------------------------------------------------------------
__global__ __launch_bounds__(256) void prep_all(
    const float* __restrict__ x, const float* __restrict__ mw,
    const float* __restrict__ ow, unsigned short* __restrict__ xt,
    unsigned short* __restrict__ wt, unsigned short* __restrict__ wot) {
  __shared__ float tile[64 * 129];
  int blk = blockIdx.x;
  int t = threadIdx.x;
  if (blk < 512) {
    const float* xrow = x + ((long)(blk >> 7) << 20) + ((blk & 127) << 7);
#pragma unroll
    for (int i = 0; i < 32; ++i) {
      int idx = t + (i << 8);          // c = idx>>7, w = idx&127
      tile[(idx >> 7) * 129 + (idx & 127)] =
          xrow[((long)(idx >> 7) << 14) + (idx & 127)];
    }
    __syncthreads();
    unsigned short* orow = xt + ((long)blk << 13);
#pragma unroll
    for (int i = 0; i < 32; ++i) {
      int idx = t + (i << 8);          // w = idx>>6, c = idx&63
      orow[idx] = f2h(tile[(idx & 63) * 129 + (idx >> 6)]);
    }
  } else {
    int idx = (blk - 512) * 256 + t;   // 0..92159
    if (idx < 73728) {
      int c = idx & 63;
      int o = (idx >> 6) & 127;
      int k = idx >> 13;
      wt[idx] = f2h(mw[o * 576 + c * 9 + k]);
    } else {
      int i2 = idx - 73728;
      int c = i2 & 63;
      int o = (i2 >> 6) & 31;
      int k = i2 >> 11;
      wot[i2] = (o < 18) ? f2h(ow[o * 576 + c * 9 + k]) : (unsigned short)0;
    }
  }
}

// ---------------------------------------------------------------------------
// Kernel B: offset conv 64->18 via f16 MFMA. Block = 32-px tile, 4 waves;
// wave wv -> (m-frag wv&1, 16-px column wv>>1). Grid 2048. No LDS/barriers.
// ---------------------------------------------------------------------------
__global__ __launch_bounds__(256) void offs_mfma(
    const unsigned short* __restrict__ xt, const unsigned short* __restrict__ wot,
    const float* __restrict__ ob, float* __restrict__ offs) {
  int l = blockIdx.x;
  int bid = ((l & 7) << 8) + (l >> 3);   // XCD swizzle
  int b = bid >> 9;
  int r9 = bid & 511;
  int h = r9 >> 2;
  int w0 = (r9 & 3) << 5;
  int t = threadIdx.x;
  int lane = t & 63;
  int wv = t >> 6;
  int mf = wv & 1;
  int pxb = w0 + ((wv >> 1) << 4);
  int l15 = lane & 15;
  int l4 = lane >> 4;
  int l4k = l4 << 3;

  f32x4 oacc = f32x4{0.f, 0.f, 0.f, 0.f};

  const unsigned short* xb = xt + ((long)b << 20);
  const unsigned short* wkb = wot + (((mf << 4) + l15) << 6) + l4k;

#pragma unroll 1
  for (int k = 0; k < 9; ++k) {
    int ky = k / 3, kx = k - 3 * ky;
    int y = h + ky - 1;
    bool yok = (unsigned)y < 128u;
    int yc = min(max(y, 0), 127);
    const unsigned short* xrow = xb + ((long)yc << 13);
    int px = pxb + l15 + kx - 1;
    bool pv = yok && ((unsigned)px < 128u);
    int pxo = min(max(px, 0), 127) << 6;
#pragma unroll
    for (int c0 = 0; c0 < 64; c0 += 32) {
      f16x8 bv = *(const f16x8*)(xrow + pxo + c0 + l4k);
      if (!pv) bv = f16x8{0, 0, 0, 0, 0, 0, 0, 0};
      f16x8 af = *(const f16x8*)(wkb + (k << 11) + c0);
      oacc = __builtin_amdgcn_mfma_f32_16x16x32_f16(af, bv, oacc, 0, 0, 0);
    }
  }

#pragma unroll
  for (int r = 0; r < 4; ++r) {
    int oc = (mf << 4) + (l4 << 2) + r;
    if (oc < 18)
      offs[((long)(b * 18 + oc) << 14) + (h << 7) + pxb + l15] = oacc[r] + ob[oc];
  }
}

// ---------------------------------------------------------------------------
// Kernel C: deformable conv via f16 MFMA (r7 structure, fp16 gather).
// Block = 64-px half-row x 128 out-ch, 4 waves, grid 1024, XCD-swizzled.
// Wave wv owns DISJOINT o-quarter (wo = wv*32, 2 m-frags) x all 64 px
// (4 n-frags) -> no wt duplication across waves.
// Double-buffered V tile; sample tap k+1 (packed __hfma2 bilinear) while
// MFMA consumes tap k. LDS: 9.2K wtab + 2x9.2K vlds = 27.6 KB -> 5 blk/CU.
// ---------------------------------------------------------------------------
__global__ __launch_bounds__(256) void deform_mfma(
    const unsigned short* __restrict__ xt, const float* __restrict__ offs,
    const unsigned short* __restrict__ wt, const float* __restrict__ mb,
    float* __restrict__ out) {
  __shared__ uint4 wtab[9][64];
  __shared__ unsigned short vlds[2][64 * 72];

  int l = blockIdx.x;
  int bid = ((l & 7) << 7) + (l >> 3);   // XCD swizzle: 128 consecutive bids/XCD
  int b = bid >> 8;
  int r8 = bid & 255;
  int h = r8 >> 1;
  int w0 = (r8 & 1) << 6;
  int t = threadIdx.x;
  int lane = t & 63;
  int wv = t >> 6;
  int wo = wv << 5;                      // disjoint o-quarter per wave
  int l15 = lane & 15;
  int l4 = lane >> 4;
  int l4k = l4 << 3;

  // ---- sampling table: 576 = 9 taps x 64 px ----
  const float* ob_ = offs + ((long)(b * 18) << 14) + (h << 7) + w0;
  for (int idx = t; idx < 576; idx += 256) {
    int px = idx & 63, k = idx >> 6;
    int ky = k / 3, kx = k - 3 * ky;
    float dy = ob_[((2 * k) << 14) + px];
    float dx = ob_[((2 * k + 1) << 14) + px];
    float py = (float)(h - 1 + ky) + dy;
    float pxf = (float)(w0 + px - 1 + kx) + dx;
    float fy = floorf(py), fx = floorf(pxf);
    float wy = py - fy, wx = pxf - fx;
    int y0 = (int)fy, x0 = (int)fx;
    int y1 = y0 + 1, x1 = x0 + 1;
    bool vy0 = (unsigned)y0 < 128u, vy1 = (unsigned)y1 < 128u;
    bool vx0 = (unsigned)x0 < 128u, vx1 = (unsigned)x1 < 128u;
    float w00 = (vy0 && vx0) ? (1.f - wy) * (1.f - wx) : 0.f;
    float w01 = (vy0 && vx1) ? (1.f - wy) * wx : 0.f;
    float w10 = (vy1 && vx0) ? wy * (1.f - wx) : 0.f;
    float w11 = (vy1 && vx1) ? wy * wx : 0.f;
    int y0c = min(max(y0, 0), 127), y1c = min(max(y1, 0), 127);
    int x0c = min(max(x0, 0), 127), x1c = min(max(x1, 0), 127);
    wtab[k][px] = make_uint4(
        (unsigned)f2h(w00) | ((unsigned)f2h(w01) << 16),
        (unsigned)f2h(w10) | ((unsigned)f2h(w11) << 16),
        (unsigned)(unsigned short)y0c | ((unsigned)(unsigned short)y1c << 16),
        (unsigned)(unsigned short)x0c | ((unsigned)(unsigned short)x1c << 16));
  }

  f32x4 acc[2][4];
#pragma unroll
  for (int m = 0; m < 2; ++m)
#pragma unroll
    for (int n = 0; n < 4; ++n) acc[m][n] = f32x4{0.f, 0.f, 0.f, 0.f};

  const unsigned short* xb = xt + ((long)b << 20);

  // sample tap k into buf: 512 units = 64 px x 8 c-chunks, 2 per thread;
  // packed __hfma2 bilinear on fp16 corner lines.
  auto sample = [&](int k, unsigned short* buf) {
#pragma unroll
    for (int it = 0; it < 2; ++it) {
      int idx2 = t + (it << 8);
      int spx = idx2 >> 3, sco = (idx2 & 7) << 3;
      uint4 e = wtab[k][spx];
      __half2 w00 = bc_h2((e.x & 0xffffu) | (e.x << 16));
      __half2 w01 = bc_h2((e.x >> 16) | (e.x & 0xffff0000u));
      __half2 w10 = bc_h2((e.y & 0xffffu) | (e.y << 16));
      __half2 w11 = bc_h2((e.y >> 16) | (e.y & 0xffff0000u));
      int y0 = (int)(short)(e.z & 0xffff), y1 = (int)(short)(e.z >> 16);
      int x0 = (int)(short)(e.w & 0xffff), x1 = (int)(short)(e.w >> 16);
      const unsigned short* r0 = xb + (y0 << 13) + sco;
      const unsigned short* r1 = xb + (y1 << 13) + sco;
      u32x4 a00 = *(const u32x4*)(r0 + (x0 << 6));
      u32x4 a01 = *(const u32x4*)(r0 + (x1 << 6));
      u32x4 a10 = *(const u32x4*)(r1 + (x0 << 6));
      u32x4 a11 = *(const u32x4*)(r1 + (x1 << 6));
      u32x4 rr;
#pragma unroll
      for (int j = 0; j < 4; ++j) {
        __half2 v = __hmul2(w00, bc_h2(a00[j]));
        v = __hfma2(w01, bc_h2(a01[j]), v);
        v = __hfma2(w10, bc_h2(a10[j]), v);
        v = __hfma2(w11, bc_h2(a11[j]), v);
        rr[j] = __builtin_bit_cast(unsigned, v);
      }
      *(u32x4*)&buf[spx * 72 + sco] = rr;
    }
  };

  __syncthreads();          // wtab ready
  sample(0, vlds[0]);
  __syncthreads();          // buf0 ready

  const unsigned short* wkb = wt + ((wo + l15) << 6) + l4k;

#pragma unroll 1
  for (int k = 0; k < 9; ++k) {
    const unsigned short* buf = vlds[k & 1];
    if (k < 8) sample(k + 1, vlds[(k + 1) & 1]);   // overlap with MFMA below

#pragma unroll
    for (int c0 = 0; c0 < 64; c0 += 32) {
      f16x8 af[2], bfr[4];
#pragma unroll
      for (int m = 0; m < 2; ++m)
        af[m] = *(const f16x8*)(wkb + (k << 13) + (m << 10) + c0);
#pragma unroll
      for (int n = 0; n < 4; ++n)
        bfr[n] = *(const f16x8*)&buf[((n << 4) + l15) * 72 + c0 + l4k];
#pragma unroll
      for (int m = 0; m < 2; ++m)
#pragma unroll
        for (int n = 0; n < 4; ++n)
          acc[m][n] = __builtin_amdgcn_mfma_f32_16x16x32_f16(
              af[m], bfr[n], acc[m][n], 0, 0, 0);
    }
    __syncthreads();        // buffer consumed / next ready
  }

  // ---- epilogue: D row = o (lane>>4)*4+reg, col = px (lane&15) ----
  int hw0 = (h << 7) + w0;
#pragma unroll
  for (int m = 0; m < 2; ++m) {
    int orow = wo + (m << 4) + (l4 << 2);
#pragma unroll
    for (int r = 0; r < 4; ++r) {
      float bias = mb[orow + r];
      long ob2 = ((long)(b * 128 + orow + r) << 14) + hw0;
#pragma unroll
      for (int n = 0; n < 4; ++n)
        out[ob2 + (n << 4) + l15] = acc[m][n][r] + bias;
    }
  }
}

extern "C" void kernel_launch(void* const* d_in, const int* in_sizes, int n_in,
                              void* d_out, int out_size, void* d_ws, size_t ws_size,
                              hipStream_t stream) {
  const float* x  = (const float*)d_in[0];
  const float* ow = (const float*)d_in[1];
  const float* ob = (const float*)d_in[2];
  const float* mw = (const float*)d_in[3];
  const float* mb = (const float*)d_in[4];
  float* out  = (float*)d_out;
  unsigned short* xt  = (unsigned short*)d_ws;                      // 8 MB
  unsigned short* wt  = (unsigned short*)((char*)d_ws + 8388608);   // 144 KB
  unsigned short* wot = (unsigned short*)((char*)d_ws + 8536064);   // 36 KB
  float* offs = (float*)((char*)d_ws + 8572928);                    // 4.5 MB

  prep_all<<<872, 256, 0, stream>>>(x, mw, ow, xt, wt, wot);
  offs_mfma<<<2048, 256, 0, stream>>>(xt, wot, ob, offs);
  deform_mfma<<<1024, 256, 0, stream>>>(xt, offs, wt, mb, out);
}

// Round 12
// 77.477 us; speedup vs baseline: 1.9082x; 1.0196x over previous
//
#include <hip/hip_runtime.h>
#include <hip/hip_fp16.h>

typedef __attribute__((ext_vector_type(8))) _Float16 f16x8;
typedef __attribute__((ext_vector_type(4))) float f32x4;
typedef __attribute__((ext_vector_type(4))) unsigned int u32x4;

__device__ __forceinline__ unsigned short f2h(float f) {
  __half h = __float2half(f);
  return __builtin_bit_cast(unsigned short, h);
}
__device__ __forceinline__ __half2 bc_h2(unsigned u) {
  return __builtin_bit_cast(__half2, u);
}

// ---------------------------------------------------------------------------
// Kernel A: prep. blocks 0..511: x NCHW fp32 -> NHWC fp16 xt[b][h][w][c].
// blocks 512..871: repack main_w -> wt[k][128][64], offset_w -> wot[k][32][64].
// ---------------------------------------------------------------------------
__global__ __launch_bounds__(256) void prep_all(
    const float* __restrict__ x, const float* __restrict__ mw,
    const float* __restrict__ ow, unsigned short* __restrict__ xt,
    unsigned short* __restrict__ wt, unsigned short* __restrict__ wot) {
  __shared__ float tile[64 * 129];
  int blk = blockIdx.x;
  int t = threadIdx.x;
  if (blk < 512) {
    const float* xrow = x + ((long)(blk >> 7) << 20) + ((blk & 127) << 7);
#pragma unroll
    for (int i = 0; i < 32; ++i) {
      int idx = t + (i << 8);          // c = idx>>7, w = idx&127
      tile[(idx >> 7) * 129 + (idx & 127)] =
          xrow[((long)(idx >> 7) << 14) + (idx & 127)];
    }
    __syncthreads();
    unsigned short* orow = xt + ((long)blk << 13);
#pragma unroll
    for (int i = 0; i < 32; ++i) {
      int idx = t + (i << 8);          // w = idx>>6, c = idx&63
      orow[idx] = f2h(tile[(idx & 63) * 129 + (idx >> 6)]);
    }
  } else {
    int idx = (blk - 512) * 256 + t;   // 0..92159
    if (idx < 73728) {
      int c = idx & 63;
      int o = (idx >> 6) & 127;
      int k = idx >> 13;
      wt[idx] = f2h(mw[o * 576 + c * 9 + k]);
    } else {
      int i2 = idx - 73728;
      int c = i2 & 63;
      int o = (i2 >> 6) & 31;
      int k = i2 >> 11;
      wot[i2] = (o < 18) ? f2h(ow[o * 576 + c * 9 + k]) : (unsigned short)0;
    }
  }
}

// ---------------------------------------------------------------------------
// Kernel B: offset conv 64->18 via f16 MFMA (r7 shape: 64-px blocks).
// Block = 64-px half-row, 4 waves; wave wv -> 16-px column, 2 m-frags.
// B-frags straight from xt (L2-hot, clamp+mask). No LDS, no barriers.
// Grid 1024, XCD-swizzled.
// ---------------------------------------------------------------------------
__global__ __launch_bounds__(256) void offs_mfma(
    const unsigned short* __restrict__ xt, const unsigned short* __restrict__ wot,
    const float* __restrict__ ob, float* __restrict__ offs) {
  int l = blockIdx.x;
  int bid = ((l & 7) << 7) + (l >> 3);   // XCD swizzle
  int b = bid >> 8;
  int r8 = bid & 255;
  int h = r8 >> 1;
  int w0 = (r8 & 1) << 6;
  int t = threadIdx.x;
  int lane = t & 63;
  int wv = t >> 6;
  int l15 = lane & 15;
  int l4 = lane >> 4;
  int l4k = l4 << 3;

  f32x4 oacc[2];
  oacc[0] = f32x4{0.f, 0.f, 0.f, 0.f};
  oacc[1] = f32x4{0.f, 0.f, 0.f, 0.f};

  const unsigned short* xb = xt + ((long)b << 20);
  const unsigned short* wkb = wot + (l15 << 6) + l4k;

#pragma unroll 1
  for (int k = 0; k < 9; ++k) {
    int ky = k / 3, kx = k - 3 * ky;
    int y = h + ky - 1;
    bool yok = (unsigned)y < 128u;
    int yc = min(max(y, 0), 127);
    const unsigned short* xrow = xb + ((long)yc << 13);
    int px = w0 + (wv << 4) + l15 + kx - 1;
    bool pv = yok && ((unsigned)px < 128u);
    int pxo = min(max(px, 0), 127) << 6;
#pragma unroll
    for (int c0 = 0; c0 < 64; c0 += 32) {
      f16x8 bv = *(const f16x8*)(xrow + pxo + c0 + l4k);
      if (!pv) bv = f16x8{0, 0, 0, 0, 0, 0, 0, 0};
#pragma unroll
      for (int m = 0; m < 2; ++m) {
        f16x8 af = *(const f16x8*)(wkb + (k << 11) + (m << 10) + c0);
        oacc[m] = __builtin_amdgcn_mfma_f32_16x16x32_f16(af, bv, oacc[m], 0, 0, 0);
      }
    }
  }

#pragma unroll
  for (int m = 0; m < 2; ++m) {
#pragma unroll
    for (int r = 0; r < 4; ++r) {
      int oc = (m << 4) + (l4 << 2) + r;
      if (oc < 18)
        offs[((long)(b * 18 + oc) << 14) + (h << 7) + w0 + (wv << 4) + l15] =
            oacc[m][r] + ob[oc];
    }
  }
}

// ---------------------------------------------------------------------------
// Kernel C: deformable conv via f16 MFMA, async-split staging (T14).
// Block = 64-px half-row x 128 out-ch, 4 waves, grid 1024, XCD-swizzled.
// Wave wv owns DISJOINT o-quarter (2 m-frags) x all 64 px (4 n-frags).
// Per tap k: (1) issue af(k) loads FIRST, (2) issue gather(k+1) loads to
// iteration-local regs, (3) sched_barrier pins order, (4) MFMA(k) runs on
// counted vmcnt while gathers fly, (5) finish(k+1): hfma2 + ds_write other
// buffer, (6) one barrier. LDS: 9.2K wtab + 2x9.2K vlds = 27.6 KB.
// ---------------------------------------------------------------------------
__global__ __launch_bounds__(256) void deform_mfma(
    const unsigned short* __restrict__ xt, const float* __restrict__ offs,
    const unsigned short* __restrict__ wt, const float* __restrict__ mb,
    float* __restrict__ out) {
  __shared__ uint4 wtab[9][64];
  __shared__ unsigned short vlds[2][64 * 72];

  int l = blockIdx.x;
  int bid = ((l & 7) << 7) + (l >> 3);   // XCD swizzle
  int b = bid >> 8;
  int r8 = bid & 255;
  int h = r8 >> 1;
  int w0 = (r8 & 1) << 6;
  int t = threadIdx.x;
  int lane = t & 63;
  int wv = t >> 6;
  int wo = wv << 5;                      // disjoint o-quarter per wave
  int l15 = lane & 15;
  int l4 = lane >> 4;
  int l4k = l4 << 3;

  // ---- sampling table: 576 = 9 taps x 64 px ----
  const float* ob_ = offs + ((long)(b * 18) << 14) + (h << 7) + w0;
  for (int idx = t; idx < 576; idx += 256) {
    int px = idx & 63, k = idx >> 6;
    int ky = k / 3, kx = k - 3 * ky;
    float dy = ob_[((2 * k) << 14) + px];
    float dx = ob_[((2 * k + 1) << 14) + px];
    float py = (float)(h - 1 + ky) + dy;
    float pxf = (float)(w0 + px - 1 + kx) + dx;
    float fy = floorf(py), fx = floorf(pxf);
    float wy = py - fy, wx = pxf - fx;
    int y0 = (int)fy, x0 = (int)fx;
    int y1 = y0 + 1, x1 = x0 + 1;
    bool vy0 = (unsigned)y0 < 128u, vy1 = (unsigned)y1 < 128u;
    bool vx0 = (unsigned)x0 < 128u, vx1 = (unsigned)x1 < 128u;
    float w00 = (vy0 && vx0) ? (1.f - wy) * (1.f - wx) : 0.f;
    float w01 = (vy0 && vx1) ? (1.f - wy) * wx : 0.f;
    float w10 = (vy1 && vx0) ? wy * (1.f - wx) : 0.f;
    float w11 = (vy1 && vx1) ? wy * wx : 0.f;
    int y0c = min(max(y0, 0), 127), y1c = min(max(y1, 0), 127);
    int x0c = min(max(x0, 0), 127), x1c = min(max(x1, 0), 127);
    wtab[k][px] = make_uint4(
        (unsigned)f2h(w00) | ((unsigned)f2h(w01) << 16),
        (unsigned)f2h(w10) | ((unsigned)f2h(w11) << 16),
        (unsigned)(unsigned short)y0c | ((unsigned)(unsigned short)y1c << 16),
        (unsigned)(unsigned short)x0c | ((unsigned)(unsigned short)x1c << 16));
  }

  const unsigned short* xb = xt + ((long)b << 20);
  int spx0 = t >> 3;                     // unit-0 px (0..31); unit-1 = +32
  int sco = (t & 7) << 3;                // 8-ch chunk offset
  __syncthreads();                       // wtab ready

  // ---- prologue: sample tap 0 into buf0 (load+finish fused) ----
  {
#pragma unroll
    for (int u = 0; u < 2; ++u) {
      int spx = spx0 + (u << 5);
      uint4 e = wtab[0][spx];
      int y0 = (int)(short)(e.z & 0xffff), y1 = (int)(short)(e.z >> 16);
      int x0 = (int)(short)(e.w & 0xffff), x1 = (int)(short)(e.w >> 16);
      const unsigned short* r0 = xb + (y0 << 13) + sco;
      const unsigned short* r1 = xb + (y1 << 13) + sco;
      u32x4 a00 = *(const u32x4*)(r0 + (x0 << 6));
      u32x4 a01 = *(const u32x4*)(r0 + (x1 << 6));
      u32x4 a10 = *(const u32x4*)(r1 + (x0 << 6));
      u32x4 a11 = *(const u32x4*)(r1 + (x1 << 6));
      __half2 w00 = bc_h2((e.x & 0xffffu) | (e.x << 16));
      __half2 w01 = bc_h2((e.x >> 16) | (e.x & 0xffff0000u));
      __half2 w10 = bc_h2((e.y & 0xffffu) | (e.y << 16));
      __half2 w11 = bc_h2((e.y >> 16) | (e.y & 0xffff0000u));
      u32x4 rr;
#pragma unroll
      for (int j = 0; j < 4; ++j) {
        __half2 v = __hmul2(w00, bc_h2(a00[j]));
        v = __hfma2(w01, bc_h2(a01[j]), v);
        v = __hfma2(w10, bc_h2(a10[j]), v);
        v = __hfma2(w11, bc_h2(a11[j]), v);
        rr[j] = __builtin_bit_cast(unsigned, v);
      }
      *(u32x4*)&vlds[0][spx * 72 + sco] = rr;
    }
  }

  f32x4 acc[2][4];
#pragma unroll
  for (int m = 0; m < 2; ++m)
#pragma unroll
    for (int n = 0; n < 4; ++n) acc[m][n] = f32x4{0.f, 0.f, 0.f, 0.f};

  const unsigned short* wkb = wt + ((wo + l15) << 6) + l4k;
  __syncthreads();                       // buf0 ready

#pragma unroll 1
  for (int k = 0; k < 9; ++k) {
    // ---- (1) af loads FIRST (counted vmcnt later leaves gathers in flight)
    f16x8 af[2][2];
#pragma unroll
    for (int c0 = 0; c0 < 2; ++c0)
#pragma unroll
      for (int m = 0; m < 2; ++m)
        af[c0][m] = *(const f16x8*)(wkb + (k << 13) + (m << 10) + (c0 << 5));

    // ---- (2) issue gather loads for tap k+1 into iteration-local regs ----
    u32x4 ga[2][4];
    uint4 ge[2];
    if (k < 8) {
#pragma unroll
      for (int u = 0; u < 2; ++u) {
        int spx = spx0 + (u << 5);
        uint4 e = wtab[k + 1][spx];
        ge[u] = e;
        int y0 = (int)(short)(e.z & 0xffff), y1 = (int)(short)(e.z >> 16);
        int x0 = (int)(short)(e.w & 0xffff), x1 = (int)(short)(e.w >> 16);
        const unsigned short* r0 = xb + (y0 << 13) + sco;
        const unsigned short* r1 = xb + (y1 << 13) + sco;
        ga[u][0] = *(const u32x4*)(r0 + (x0 << 6));
        ga[u][1] = *(const u32x4*)(r0 + (x1 << 6));
        ga[u][2] = *(const u32x4*)(r1 + (x0 << 6));
        ga[u][3] = *(const u32x4*)(r1 + (x1 << 6));
      }
    }
    __builtin_amdgcn_sched_barrier(0);   // pin: loads above, MFMA below

    // ---- (4) MFMA tap k from buf[k&1] ----
    const unsigned short* buf = vlds[k & 1];
#pragma unroll
    for (int c0 = 0; c0 < 2; ++c0) {
      f16x8 bfr[4];
#pragma unroll
      for (int n = 0; n < 4; ++n)
        bfr[n] = *(const f16x8*)&buf[((n << 4) + l15) * 72 + (c0 << 5) + l4k];
#pragma unroll
      for (int m = 0; m < 2; ++m)
#pragma unroll
        for (int n = 0; n < 4; ++n)
          acc[m][n] = __builtin_amdgcn_mfma_f32_16x16x32_f16(
              af[c0][m], bfr[n], acc[m][n], 0, 0, 0);
    }

    // ---- (5) finish tap k+1: bilinear + ds_write other buffer ----
    if (k < 8) {
      unsigned short* nbuf = vlds[(k + 1) & 1];
#pragma unroll
      for (int u = 0; u < 2; ++u) {
        uint4 e = ge[u];
        __half2 w00 = bc_h2((e.x & 0xffffu) | (e.x << 16));
        __half2 w01 = bc_h2((e.x >> 16) | (e.x & 0xffff0000u));
        __half2 w10 = bc_h2((e.y & 0xffffu) | (e.y << 16));
        __half2 w11 = bc_h2((e.y >> 16) | (e.y & 0xffff0000u));
        u32x4 rr;
#pragma unroll
        for (int j = 0; j < 4; ++j) {
          __half2 v = __hmul2(w00, bc_h2(ga[u][0][j]));
          v = __hfma2(w01, bc_h2(ga[u][1][j]), v);
          v = __hfma2(w10, bc_h2(ga[u][2][j]), v);
          v = __hfma2(w11, bc_h2(ga[u][3][j]), v);
          rr[j] = __builtin_bit_cast(unsigned, v);
        }
        *(u32x4*)&nbuf[(spx0 + (u << 5)) * 72 + sco] = rr;
      }
    }
    __syncthreads();        // (6) buffer handoff
  }

  // ---- epilogue: D row = o (lane>>4)*4+reg, col = px (lane&15) ----
  int hw0 = (h << 7) + w0;
#pragma unroll
  for (int m = 0; m < 2; ++m) {
    int orow = wo + (m << 4) + (l4 << 2);
#pragma unroll
    for (int r = 0; r < 4; ++r) {
      float bias = mb[orow + r];
      long ob2 = ((long)(b * 128 + orow + r) << 14) + hw0;
#pragma unroll
      for (int n = 0; n < 4; ++n)
        out[ob2 + (n << 4) + l15] = acc[m][n][r] + bias;
    }
  }
}

extern "C" void kernel_launch(void* const* d_in, const int* in_sizes, int n_in,
                              void* d_out, int out_size, void* d_ws, size_t ws_size,
                              hipStream_t stream) {
  const float* x  = (const float*)d_in[0];
  const float* ow = (const float*)d_in[1];
  const float* ob = (const float*)d_in[2];
  const float* mw = (const float*)d_in[3];
  const float* mb = (const float*)d_in[4];
  float* out  = (float*)d_out;
  unsigned short* xt  = (unsigned short*)d_ws;                      // 8 MB
  unsigned short* wt  = (unsigned short*)((char*)d_ws + 8388608);   // 144 KB
  unsigned short* wot = (unsigned short*)((char*)d_ws + 8536064);   // 36 KB
  float* offs = (float*)((char*)d_ws + 8572928);                    // 4.5 MB

  prep_all<<<872, 256, 0, stream>>>(x, mw, ow, xt, wt, wot);
  offs_mfma<<<1024, 256, 0, stream>>>(xt, wot, ob, offs);
  deform_mfma<<<1024, 256, 0, stream>>>(xt, offs, wt, mb, out);
}